// Round 10
// baseline (3112.683 us; speedup 1.0000x reference)
//
#include <hip/hip_runtime.h>
#include <stdint.h>

#define B_  64
#define T_  512
#define I_  512
#define H_  1024
#define G4  4096
#define KW  1536   // rows of W_t = I_ + H_

#define GROUPS 4
#define GBLK   32    // col-blocks per group
#define MBR    16    // batch rows per group

#define LDS_BYTES 82432

typedef __attribute__((ext_vector_type(8))) short bf16x8;
typedef __attribute__((ext_vector_type(4))) float f32x4;

// ---- ws layout (bytes) ----
#define OFF_WT   ((size_t)0)                        // 4096*1536*2 = 12,582,912
#define OFF_XB   ((size_t)(16u << 20))              // x bf16: 33,554,432
#define OFF_HB   (OFF_XB + (size_t)33554432)        // tagged h: 2 par * 4 grp * 16 * 1024 * 2B
#define WS_NEED  (OFF_HB + (size_t)262144)

__device__ __forceinline__ unsigned short f2bf(float x) {
  unsigned u = __float_as_uint(x);
  u += 0x7FFFu + ((u >> 16) & 1u);        // RNE
  return (unsigned short)(u >> 16);
}
__device__ __forceinline__ float sigm(float x) {
  return 1.0f / (1.0f + __expf(-x));
}
__device__ __forceinline__ float fast_tanh(float x) {
  const float e2 = __expf(2.0f * x);
  return 1.0f - 2.0f / (e2 + 1.0f);
}

// ============ kernel 0: pack [U;V] -> W_t[col][k] bf16 (transposed) ============
__global__ __launch_bounds__(256) void pack_w_kernel(
    const float* __restrict__ U0, const float* __restrict__ U1,
    const float* __restrict__ U2, const float* __restrict__ U3,
    const float* __restrict__ V0, const float* __restrict__ V1,
    const float* __restrict__ V2, const float* __restrict__ V3,
    short* __restrict__ Wt)
{
  __shared__ short sl[64][65];
  const int c0 = blockIdx.x * 64;
  const int k0 = blockIdx.y * 64;
  const int g  = c0 >> 10;
  const int h0 = c0 & 1023;
  const float* srcU = (g == 0 ? U0 : g == 1 ? U1 : g == 2 ? U2 : U3);
  const float* srcV = (g == 0 ? V0 : g == 1 ? V1 : g == 2 ? V2 : V3);
  const float* src  = (k0 < 512) ? (srcU + (size_t)k0 * H_)
                                 : (srcV + (size_t)(k0 - 512) * H_);
  const int tid = threadIdx.x;
  const int cl = tid & 63;
  const int r4 = tid >> 6;
  #pragma unroll
  for (int r = 0; r < 16; ++r) {
    const int kl = r * 4 + r4;
    sl[kl][cl] = (short)f2bf(src[(size_t)kl * H_ + h0 + cl]);
  }
  __syncthreads();
  #pragma unroll
  for (int r = 0; r < 16; ++r) {
    const int cl2 = r * 4 + r4;
    Wt[(size_t)(c0 + cl2) * KW + k0 + cl] = sl[cl][cl2];
  }
}

// ============ kernel 1: x fp32 -> bf16 ============
__global__ __launch_bounds__(256) void xcvt(
    const float* __restrict__ x, short* __restrict__ xb)
{
  const int nt = 524288;
  const int idx = blockIdx.x * 256 + threadIdx.x;
  #pragma unroll
  for (int i = 0; i < 8; ++i) {
    const int j = idx + i * nt;
    const float4 v = ((const float4*)x)[j];
    uint2 pk;
    pk.x = (unsigned)f2bf(v.x) | ((unsigned)f2bf(v.y) << 16);
    pk.y = (unsigned)f2bf(v.z) | ((unsigned)f2bf(v.w) << 16);
    ((uint2*)xb)[j] = pk;
  }
}

// fragment address (shorts): slot XOR-swizzled within unit
#define FR_ADDR(unit, slot) ((((unit) * 64) + ((slot) ^ ((unit) & 7))) * 8)

#define MFMA_ __builtin_amdgcn_mfma_f32_16x16x32_bf16

// ============ kernel 2: persistent recurrence; 128 blocks x 32 h-cols ============
__global__ __launch_bounds__(512, 2) void lstm_rec(
    const short* __restrict__ Wt, const short* __restrict__ xb,
    const float* __restrict__ b0g, const float* __restrict__ b1g,
    const float* __restrict__ b2g, const float* __restrict__ b3g,
    short* __restrict__ hb, float* __restrict__ out)
{
  extern __shared__ char smem[];
  short* sh = (short*)smem;                 // 32 KiB h frags (32 units x 64 slots x 16B)
  short* sx = (short*)(smem + 32768);       // 16 KiB x frags (16 units)
  float* gl = (float*)(smem + 49152);       // [16 rows][520] f32 partial-gate exchange

  const int tid = threadIdx.x;
  const int blk = blockIdx.x;
  const int g   = blk >> 5;                 // group (16 batch rows)
  const int bi  = blk & 31;
  const int base = bi * 32;                 // 32 h-cols per block per gate
  const int b0  = g * MBR;

  const int w = tid >> 6, l = tid & 63;
  const int kq = w & 3;                     // K quarter (256 of V-K, 128 of x-K)
  const int np = w >> 2;                    // gate pair: {0,1} or {2,3}
  const int cit = l & 15;
  const int l16 = l >> 4;
  const int slot_r = (cit << 2) | l16;

  // ---- one-time: V fragments -> 128 VGPRs, U fragments -> 64 VGPRs ----
  // tiles: 0 = gate np*2 hc[0..15], 1 = gate np*2 hc[16..31], 2/3 = gate np*2+1
  bf16x8 vfr0[8], vfr1[8], vfr2[8], vfr3[8];
  bf16x8 ufr0[4], ufr1[4], ufr2[4], ufr3[4];
  {
    const int g0_ = np * 2, g1_ = np * 2 + 1;
    const short* wp0 = Wt + (size_t)(g0_ * 1024 + base + cit) * KW;
    const short* wp1 = Wt + (size_t)(g0_ * 1024 + base + 16 + cit) * KW;
    const short* wp2 = Wt + (size_t)(g1_ * 1024 + base + cit) * KW;
    const short* wp3 = Wt + (size_t)(g1_ * 1024 + base + 16 + cit) * KW;
    #pragma unroll
    for (int j = 0; j < 8; ++j) {
      const int o = 512 + kq * 256 + j * 32 + l16 * 8;
      vfr0[j] = *(const bf16x8*)(wp0 + o);
      vfr1[j] = *(const bf16x8*)(wp1 + o);
      vfr2[j] = *(const bf16x8*)(wp2 + o);
      vfr3[j] = *(const bf16x8*)(wp3 + o);
    }
    #pragma unroll
    for (int j = 0; j < 4; ++j) {
      const int o = kq * 128 + j * 32 + l16 * 8;
      ufr0[j] = *(const bf16x8*)(wp0 + o);
      ufr1[j] = *(const bf16x8*)(wp1 + o);
      ufr2[j] = *(const bf16x8*)(wp2 + o);
      ufr3[j] = *(const bf16x8*)(wp3 + o);
    }
  }
  const float* bp0 = (np == 0) ? b0g : b2g;
  const float* bp1 = (np == 0) ? b1g : b3g;
  const float bv0 = (kq == 0) ? bp0[base + cit] : 0.0f;
  const float bv1 = (kq == 0) ? bp0[base + 16 + cit] : 0.0f;
  const float bv2 = (kq == 0) ? bp1[base + cit] : 0.0f;
  const float bv3 = (kq == 0) ? bp1[base + 16 + cit] : 0.0f;

  const int crow = tid >> 5;                // combine row 0..15
  const int ccol = tid & 31;                // combine h-col 0..31

  // x-staging geometry (two 16B fragments per thread)
  const int xr0_row = tid >> 6;
  const int xr1_row = 8 + (tid >> 6);
  const int x_k0 = (tid & 63) * 8;
  const int x_unit = x_k0 >> 5;
  const int xr0_addr = FR_ADDR(x_unit, (xr0_row << 2) | (tid & 3));
  const int xr1_addr = FR_ADDR(x_unit, (xr1_row << 2) | (tid & 3));
  const short* xsrc0 = xb + (size_t)(b0 + xr0_row) * T_ * I_ + x_k0;
  const short* xsrc1 = xb + (size_t)(b0 + xr1_row) * T_ * I_ + x_k0;

  float c_state = 0.0f;

  // ---- prologue: stage x(0), xu(0), prefetch x(1) ----
  *(int4*)(sx + xr0_addr) = *(const int4*)(xsrc0);
  *(int4*)(sx + xr1_addr) = *(const int4*)(xsrc1);
  __syncthreads();
  f32x4 xa0 = (f32x4){bv0, bv0, bv0, bv0};
  f32x4 xa1 = (f32x4){bv1, bv1, bv1, bv1};
  f32x4 xa2 = (f32x4){bv2, bv2, bv2, bv2};
  f32x4 xa3 = (f32x4){bv3, bv3, bv3, bv3};
  #pragma unroll
  for (int j = 0; j < 4; ++j) {
    const bf16x8 xf = *(const bf16x8*)(sx + FR_ADDR(kq * 4 + j, slot_r));
    xa0 = MFMA_(xf, ufr0[j], xa0, 0, 0, 0);
    xa1 = MFMA_(xf, ufr1[j], xa1, 0, 0, 0);
    xa2 = MFMA_(xf, ufr2[j], xa2, 0, 0, 0);
    xa3 = MFMA_(xf, ufr3[j], xa3, 0, 0, 0);
  }
  int4 xr0 = *(const int4*)(xsrc0 + (size_t)1 * I_);
  int4 xr1 = *(const int4*)(xsrc1 + (size_t)1 * I_);

  for (int t = 0; t < T_; ++t) {
    { // ---- A: retry-load h(t) until step-tag bits match, then stage to sh ----
      const unsigned expw = ((t >> 1) & 1) ? 0x00010001u : 0u;
      const short* hsrc = hb + ((size_t)(t & 1) * GROUPS + g) * (MBR * H_);
      int4 v0, v1, v2, v3;
      for (;;) {
        #define LDC(ii, vv) { \
          const short* p = hsrc + (size_t)((((ii) * 512 + tid) >> 7)) * H_ \
                           + ((((ii) * 512 + tid) & 127) * 8); \
          asm volatile("global_load_dwordx4 %0, %1, off sc0 sc1" : "=&v"(vv) : "v"(p)); }
        LDC(0, v0) LDC(1, v1) LDC(2, v2) LDC(3, v3)
        #undef LDC
        asm volatile("s_waitcnt vmcnt(0)" ::: "memory");
        __builtin_amdgcn_sched_barrier(0);
        #define XR(vv) (((unsigned)(vv).x ^ expw) | ((unsigned)(vv).y ^ expw) | \
                        ((unsigned)(vv).z ^ expw) | ((unsigned)(vv).w ^ expw))
        const unsigned diff = (XR(v0) | XR(v1) | XR(v2) | XR(v3)) & 0x00010001u;
        #undef XR
        if (__all(diff == 0u)) break;
        asm volatile("s_sleep 1" ::: "memory");
      }
      #define STC(ii, vv) { const int f = (ii) * 512 + tid; const int row = f >> 7; \
        const int k0s = (f & 127) * 8; \
        *(int4*)(sh + FR_ADDR(k0s >> 5, (row << 2) | ((k0s >> 3) & 3))) = vv; }
      STC(0, v0) STC(1, v1) STC(2, v2) STC(3, v3)
      #undef STC
    }
    __syncthreads();                                   // barrier 1

    // ---- B: partial gates = xu_part + h @ V_part (V from registers) ----
    f32x4 a0 = xa0, a1 = xa1, a2 = xa2, a3 = xa3;
    #pragma unroll
    for (int j = 0; j < 8; ++j) {
      const bf16x8 af = *(const bf16x8*)(sh + FR_ADDR(kq * 8 + j, slot_r));
      a0 = MFMA_(af, vfr0[j], a0, 0, 0, 0);
      a1 = MFMA_(af, vfr1[j], a1, 0, 0, 0);
      a2 = MFMA_(af, vfr2[j], a2, 0, 0, 0);
      a3 = MFMA_(af, vfr3[j], a3, 0, 0, 0);
    }

    // ---- C: 4-way partial exchange; layout [row][ (gate*32+hc)*4 + kq ] ----
    {
      const int g0_ = np * 2, g1_ = np * 2 + 1;
      #pragma unroll
      for (int e = 0; e < 4; ++e) {
        const int rr = (l16 * 4 + e) * 520;
        gl[rr + (g0_ * 32 + cit) * 4 + kq]      = a0[e];
        gl[rr + (g0_ * 32 + 16 + cit) * 4 + kq] = a1[e];
        gl[rr + (g1_ * 32 + cit) * 4 + kq]      = a2[e];
        gl[rr + (g1_ * 32 + 16 + cit) * 4 + kq] = a3[e];
      }
    }
    __syncthreads();                                   // barrier 2

    // ---- D: combine (all 512 threads); fire-and-forget tagged h stores ----
    {
      const float* gr = gl + crow * 520;
      const f32x4 si = *(const f32x4*)(gr + (0 * 32 + ccol) * 4);
      const f32x4 sf = *(const f32x4*)(gr + (1 * 32 + ccol) * 4);
      const f32x4 sg = *(const f32x4*)(gr + (2 * 32 + ccol) * 4);
      const f32x4 so = *(const f32x4*)(gr + (3 * 32 + ccol) * 4);
      const float s0 = si[0] + si[1] + si[2] + si[3];
      const float s1 = sf[0] + sf[1] + sf[2] + sf[3];
      const float s2 = sg[0] + sg[1] + sg[2] + sg[3];
      const float s3 = so[0] + so[1] + so[2] + so[3];
      const float i_ = sigm(s0), f_ = sigm(s1), g_ = sigm(s2), o_ = sigm(s3);
      c_state = f_ * c_state + i_ * g_;
      const float hval = o_ * fast_tanh(c_state);
      if (t + 1 < T_) {
        unsigned hv = (unsigned)f2bf(hval);
        hv = (hv & ~1u) | (unsigned)(((t + 1) >> 1) & 1);   // steal LSB as step tag
        short* hdst = hb + ((size_t)((t + 1) & 1) * GROUPS + g) * (MBR * H_)
                      + (size_t)crow * H_ + base + ccol;
        asm volatile("global_store_short %0, %1, off sc0 sc1" :: "v"(hdst), "v"(hv) : "memory");
      }
      out[((size_t)(b0 + crow) << 19) + (size_t)t * H_ + base + ccol] = hval;
      if (t == T_ - 1) {
        out[(size_t)B_ * T_ * H_ + (size_t)(b0 + crow) * H_ + base + ccol] = hval;
        out[(size_t)B_ * T_ * H_ + (size_t)B_ * H_ + (size_t)(b0 + crow) * H_ + base + ccol] = c_state;
      }
    }

    if (t + 1 < T_) {
      // ---- E: write prefetched x(t+1), prefetch x(t+2) ----
      *(int4*)(sx + xr0_addr) = xr0;
      *(int4*)(sx + xr1_addr) = xr1;
      {
        const size_t tn = (size_t)((t + 2 < T_) ? t + 2 : T_ - 1);
        xr0 = *(const int4*)(xsrc0 + tn * I_);
        xr1 = *(const int4*)(xsrc1 + tn * I_);
      }
      __syncthreads();                                 // barrier 3

      // ---- F: xu(t+1) partial = bias + x(t+1) @ U_part ----
      xa0 = (f32x4){bv0, bv0, bv0, bv0};
      xa1 = (f32x4){bv1, bv1, bv1, bv1};
      xa2 = (f32x4){bv2, bv2, bv2, bv2};
      xa3 = (f32x4){bv3, bv3, bv3, bv3};
      #pragma unroll
      for (int j = 0; j < 4; ++j) {
        const bf16x8 xf = *(const bf16x8*)(sx + FR_ADDR(kq * 4 + j, slot_r));
        xa0 = MFMA_(xf, ufr0[j], xa0, 0, 0, 0);
        xa1 = MFMA_(xf, ufr1[j], xa1, 0, 0, 0);
        xa2 = MFMA_(xf, ufr2[j], xa2, 0, 0, 0);
        xa3 = MFMA_(xf, ufr3[j], xa3, 0, 0, 0);
      }
    }
  }
}

extern "C" void kernel_launch(void* const* d_in, const int* in_sizes, int n_in,
                              void* d_out, int out_size, void* d_ws, size_t ws_size,
                              hipStream_t stream)
{
  const float* x  = (const float*)d_in[0];
  const float* U0 = (const float*)d_in[1];
  const float* Vg0 = (const float*)d_in[2];
  const float* bg0 = (const float*)d_in[3];
  const float* U1 = (const float*)d_in[4];
  const float* Vg1 = (const float*)d_in[5];
  const float* bg1 = (const float*)d_in[6];
  const float* U2 = (const float*)d_in[7];
  const float* Vg2 = (const float*)d_in[8];
  const float* bg2 = (const float*)d_in[9];
  const float* U3 = (const float*)d_in[10];
  const float* Vg3 = (const float*)d_in[11];
  const float* bg3 = (const float*)d_in[12];

  if (ws_size < WS_NEED) return;  // diagnostic: leaves d_out poisoned

  char* ws = (char*)d_ws;
  short* Wt = (short*)(ws + OFF_WT);
  short* xb = (short*)(ws + OFF_XB);
  short* hb = (short*)(ws + OFF_HB);

  (void)hipFuncSetAttribute((const void*)lstm_rec,
                      hipFuncAttributeMaxDynamicSharedMemorySize, LDS_BYTES);

  // parity 0: zeros -> valid h(0)=0, tag 0. parity 1: 0x0101 -> stale until h(1) lands.
  (void)hipMemsetAsync(ws + OFF_HB, 0x00, 131072, stream);
  (void)hipMemsetAsync(ws + OFF_HB + 131072, 0x01, 131072, stream);
  pack_w_kernel<<<dim3(64, 24), 256, 0, stream>>>(U0, U1, U2, U3, Vg0, Vg1, Vg2, Vg3, Wt);
  xcvt<<<dim3(2048), 256, 0, stream>>>(x, xb);
  lstm_rec<<<dim3(GROUPS * GBLK), 512, LDS_BYTES, stream>>>(
      Wt, xb, bg0, bg1, bg2, bg3, hb, (float*)d_out);
}

// Round 11
// 2526.195 us; speedup vs baseline: 1.2322x; 1.2322x over previous
//
#include <hip/hip_runtime.h>
#include <stdint.h>

#define B_  64
#define T_  512
#define I_  512
#define H_  1024
#define KW  1536   // rows of W_t = I_ + H_

#define GROUPS 4
#define GBLK   64    // col-blocks per group
#define MBR    16    // batch rows per group

#define GLSTR 524    // gl row stride (floats); 524*4B, 16B-aligned, mod32=12
#define LDS_BYTES (2 * 16 * GLSTR * 4)

typedef __attribute__((ext_vector_type(8))) short bf16x8;
typedef __attribute__((ext_vector_type(4))) float f32x4;

// ---- ws layout (bytes) ----
#define OFF_WT   ((size_t)0)                        // 4096*1536*2 = 12,582,912
#define OFF_XB   ((size_t)(16u << 20))              // x bf16: 33,554,432
#define OFF_HB   (OFF_XB + (size_t)33554432)        // tagged h: 2 par * 4 grp * 16 * 1024 * 2B
#define WS_NEED  (OFF_HB + (size_t)262144)

__device__ __forceinline__ unsigned short f2bf(float x) {
  unsigned u = __float_as_uint(x);
  u += 0x7FFFu + ((u >> 16) & 1u);        // RNE
  return (unsigned short)(u >> 16);
}
__device__ __forceinline__ float sigm(float x) {
  return 1.0f / (1.0f + __expf(-x));
}
__device__ __forceinline__ float fast_tanh(float x) {
  const float e2 = __expf(2.0f * x);
  return 1.0f - 2.0f / (e2 + 1.0f);
}
__device__ __forceinline__ bf16x8 bc8(int4 v) {
  union { int4 i; bf16x8 b; } u; u.i = v; return u.b;
}

// ============ kernel 0: pack [U;V] -> W_t[col][k] bf16 (transposed) ============
__global__ __launch_bounds__(256) void pack_w_kernel(
    const float* __restrict__ U0, const float* __restrict__ U1,
    const float* __restrict__ U2, const float* __restrict__ U3,
    const float* __restrict__ V0, const float* __restrict__ V1,
    const float* __restrict__ V2, const float* __restrict__ V3,
    short* __restrict__ Wt)
{
  __shared__ short sl[64][65];
  const int c0 = blockIdx.x * 64;
  const int k0 = blockIdx.y * 64;
  const int g  = c0 >> 10;
  const int h0 = c0 & 1023;
  const float* srcU = (g == 0 ? U0 : g == 1 ? U1 : g == 2 ? U2 : U3);
  const float* srcV = (g == 0 ? V0 : g == 1 ? V1 : g == 2 ? V2 : V3);
  const float* src  = (k0 < 512) ? (srcU + (size_t)k0 * H_)
                                 : (srcV + (size_t)(k0 - 512) * H_);
  const int tid = threadIdx.x;
  const int cl = tid & 63;
  const int r4 = tid >> 6;
  #pragma unroll
  for (int r = 0; r < 16; ++r) {
    const int kl = r * 4 + r4;
    sl[kl][cl] = (short)f2bf(src[(size_t)kl * H_ + h0 + cl]);
  }
  __syncthreads();
  #pragma unroll
  for (int r = 0; r < 16; ++r) {
    const int cl2 = r * 4 + r4;
    Wt[(size_t)(c0 + cl2) * KW + k0 + cl] = sl[cl][cl2];
  }
}

// ============ kernel 1: x fp32 -> bf16 ============
__global__ __launch_bounds__(256) void xcvt(
    const float* __restrict__ x, short* __restrict__ xb)
{
  const int nt = 524288;
  const int idx = blockIdx.x * 256 + threadIdx.x;
  #pragma unroll
  for (int i = 0; i < 8; ++i) {
    const int j = idx + i * nt;
    const float4 v = ((const float4*)x)[j];
    uint2 pk;
    pk.x = (unsigned)f2bf(v.x) | ((unsigned)f2bf(v.y) << 16);
    pk.y = (unsigned)f2bf(v.z) | ((unsigned)f2bf(v.w) << 16);
    ((uint2*)xb)[j] = pk;
  }
}

#define MFMA_ __builtin_amdgcn_mfma_f32_16x16x32_bf16
#define LDH(vv, p) asm volatile("global_load_dwordx4 %0, %1, off sc0 sc1" : "=&v"(vv) : "v"(p));
#define XRT(vv, ew) ((((unsigned)(vv).x ^ (ew)) | ((unsigned)(vv).y ^ (ew)) | \
                      ((unsigned)(vv).z ^ (ew)) | ((unsigned)(vv).w ^ (ew))) & 0x00010001u)

// ============ kernel 2: persistent recurrence; h loads ARE the MFMA fragments ============
__global__ __launch_bounds__(512, 1) void lstm_rec(
    const short* __restrict__ Wt, const short* __restrict__ xb,
    const float* __restrict__ b0g, const float* __restrict__ b1g,
    const float* __restrict__ b2g, const float* __restrict__ b3g,
    short* __restrict__ hb, float* __restrict__ out)
{
  extern __shared__ char smem[];
  float* glA = (float*)smem;                       // [16][GLSTR] partials, even t
  float* glB = (float*)(smem + 16 * GLSTR * 4);    // odd t

  const int tid = threadIdx.x;
  const int blk = blockIdx.x;
  const int g   = blk >> 6;                 // group (16 batch rows)
  const int bi  = blk & 63;
  const int base = bi * 16;                 // 16 h-cols per block per gate
  const int b0  = g * MBR;

  const int w = tid >> 6, l = tid & 63;
  const int kqe = w;                        // K-eighth: V-K 128, x-K 64
  const int cit = l & 15;
  const int l16 = l >> 4;

  // ---- one-time: V fragments (64 VGPR) + U fragments (32 VGPR) ----
  bf16x8 vfr[4][4];     // [gate][j]  (K-eighth = 4 x 32)
  bf16x8 ufr[4][2];     // [gate][j]  (x K-eighth = 2 x 32)
  float bv[4];
  #pragma unroll
  for (int gate = 0; gate < 4; ++gate) {
    const short* wp = Wt + (size_t)(gate * 1024 + base + cit) * KW;
    #pragma unroll
    for (int j = 0; j < 4; ++j)
      vfr[gate][j] = *(const bf16x8*)(wp + 512 + kqe * 128 + j * 32 + l16 * 8);
    #pragma unroll
    for (int j = 0; j < 2; ++j)
      ufr[gate][j] = *(const bf16x8*)(wp + kqe * 64 + j * 32 + l16 * 8);
    const float* bp = (gate == 0 ? b0g : gate == 1 ? b1g : gate == 2 ? b2g : b3g);
    bv[gate] = (kqe == 0) ? bp[base + cit] : 0.0f;
  }

  // ---- h fragment addressing (per-lane, coherent, IS the MFMA A-fragment) ----
  const int hoff0 = cit * H_ + kqe * 128 + 0 * 32 + l16 * 8;
  const int hoff1 = cit * H_ + kqe * 128 + 1 * 32 + l16 * 8;
  const int hoff2 = cit * H_ + kqe * 128 + 2 * 32 + l16 * 8;
  const int hoff3 = cit * H_ + kqe * 128 + 3 * 32 + l16 * 8;
  const short* hbase0 = hb + g * (MBR * H_);
  const short* hbase1 = hb + 65536 + g * (MBR * H_);

  // ---- x fragment addressing (plain loads, direct to regs) ----
  const short* xsrc = xb + (size_t)(b0 + cit) * T_ * I_ + kqe * 64 + l16 * 8;

  const int crow = tid >> 4;                // combine row (tid<256)
  const int ccol = tid & 15;

  float c_state = 0.0f;
  int4 hv0, hv1, hv2, hv3;
  f32x4 xacc[4], acc[4];

  // ---- prologue: xu(0) from x(0); prefetch x(1); issue h(0) loads ----
  int4 nx0, nx1;
  {
    const int4 a0 = *(const int4*)(xsrc);
    const int4 a1 = *(const int4*)(xsrc + 32);
    #pragma unroll
    for (int gate = 0; gate < 4; ++gate) {
      xacc[gate] = (f32x4){bv[gate], bv[gate], bv[gate], bv[gate]};
      xacc[gate] = MFMA_(bc8(a0), ufr[gate][0], xacc[gate], 0, 0, 0);
      xacc[gate] = MFMA_(bc8(a1), ufr[gate][1], xacc[gate], 0, 0, 0);
    }
    nx0 = *(const int4*)(xsrc + I_);
    nx1 = *(const int4*)(xsrc + I_ + 32);
  }
  LDH(hv0, hbase0 + hoff0) LDH(hv1, hbase0 + hoff1)
  LDH(hv2, hbase0 + hoff2) LDH(hv3, hbase0 + hoff3)

  for (int t = 0; t < T_; ++t) {
    // ---- A: tag-check in-flight h(t) fragments; retry on miss ----
    {
      const unsigned ew = ((t >> 1) & 1) ? 0x00010001u : 0u;
      const short* hc = (t & 1) ? hbase1 : hbase0;
      asm volatile("s_waitcnt vmcnt(0)" ::: "memory");
      __builtin_amdgcn_sched_barrier(0);
      while (!__all((XRT(hv0, ew) | XRT(hv1, ew) | XRT(hv2, ew) | XRT(hv3, ew)) == 0u)) {
        asm volatile("s_sleep 1" ::: "memory");
        LDH(hv0, hc + hoff0) LDH(hv1, hc + hoff1)
        LDH(hv2, hc + hoff2) LDH(hv3, hc + hoff3)
        asm volatile("s_waitcnt vmcnt(0)" ::: "memory");
        __builtin_amdgcn_sched_barrier(0);
      }
    }

    // ---- B: partial gates = xu_part + h @ V_part (all operands in registers) ----
    #pragma unroll
    for (int gate = 0; gate < 4; ++gate) acc[gate] = xacc[gate];
    {
      const bf16x8 a0 = bc8(hv0), a1 = bc8(hv1), a2 = bc8(hv2), a3 = bc8(hv3);
      #pragma unroll
      for (int gate = 0; gate < 4; ++gate) {
        acc[gate] = MFMA_(a0, vfr[gate][0], acc[gate], 0, 0, 0);
        acc[gate] = MFMA_(a1, vfr[gate][1], acc[gate], 0, 0, 0);
        acc[gate] = MFMA_(a2, vfr[gate][2], acc[gate], 0, 0, 0);
        acc[gate] = MFMA_(a3, vfr[gate][3], acc[gate], 0, 0, 0);
      }
    }

    // ---- C: 8-way partial exchange (double-buffered -> one barrier/step) ----
    float* glw = (t & 1) ? glB : glA;
    #pragma unroll
    for (int e = 0; e < 4; ++e) {
      float* gr = glw + (l16 * 4 + e) * GLSTR + cit * 8 + kqe;
      gr[0 * 128] = acc[0][e];
      gr[1 * 128] = acc[1][e];
      gr[2 * 128] = acc[2][e];
      gr[3 * 128] = acc[3][e];
    }
    __syncthreads();                                   // the only barrier per step

    // ---- D: combine; fire-and-forget tagged h stores; out stores ----
    if (tid < 256) {
      const float* gr = glw + crow * GLSTR + ccol * 8;
      float s[4];
      #pragma unroll
      for (int gate = 0; gate < 4; ++gate) {
        const f32x4 u = *(const f32x4*)(gr + gate * 128);
        const f32x4 v = *(const f32x4*)(gr + gate * 128 + 4);
        s[gate] = (u[0] + u[1]) + (u[2] + u[3]) + (v[0] + v[1]) + (v[2] + v[3]);
      }
      const float i_ = sigm(s[0]), f_ = sigm(s[1]), g_ = sigm(s[2]), o_ = sigm(s[3]);
      c_state = f_ * c_state + i_ * g_;
      const float hval = o_ * fast_tanh(c_state);
      if (t + 1 < T_) {
        unsigned hu = (unsigned)f2bf(hval);
        hu = (hu & ~1u) | (unsigned)(((t + 1) >> 1) & 1);   // steal LSB as step tag
        short* hd = hb + (size_t)(((t + 1) & 1) * GROUPS + g) * (MBR * H_)
                    + (size_t)crow * H_ + base + ccol;
        asm volatile("global_store_short %0, %1, off sc0 sc1" :: "v"(hd), "v"(hu) : "memory");
      }
      out[((size_t)(b0 + crow) << 19) + (size_t)t * H_ + base + ccol] = hval;
      if (t == T_ - 1) {
        out[(size_t)B_ * T_ * H_ + (size_t)(b0 + crow) * H_ + base + ccol] = hval;
        out[(size_t)B_ * T_ * H_ + (size_t)B_ * H_ + (size_t)(b0 + crow) * H_ + base + ccol] = c_state;
      }
    }

    if (t + 1 < T_) {
      // ---- E: issue h(t+1) fragment loads (hidden under F + loop-around) ----
      {
        const short* hn = ((t + 1) & 1) ? hbase1 : hbase0;
        LDH(hv0, hn + hoff0) LDH(hv1, hn + hoff1)
        LDH(hv2, hn + hoff2) LDH(hv3, hn + hoff3)
      }
      // ---- F: xu(t+1) from prefetched x; prefetch x(t+2) ----
      {
        const int4 c0 = nx0, c1 = nx1;
        #pragma unroll
        for (int gate = 0; gate < 4; ++gate) {
          xacc[gate] = (f32x4){bv[gate], bv[gate], bv[gate], bv[gate]};
          xacc[gate] = MFMA_(bc8(c0), ufr[gate][0], xacc[gate], 0, 0, 0);
          xacc[gate] = MFMA_(bc8(c1), ufr[gate][1], xacc[gate], 0, 0, 0);
        }
        const size_t tn = (size_t)((t + 2 < T_) ? t + 2 : T_ - 1);
        nx0 = *(const int4*)(xsrc + tn * I_);
        nx1 = *(const int4*)(xsrc + tn * I_ + 32);
      }
    }
  }
}

extern "C" void kernel_launch(void* const* d_in, const int* in_sizes, int n_in,
                              void* d_out, int out_size, void* d_ws, size_t ws_size,
                              hipStream_t stream)
{
  const float* x  = (const float*)d_in[0];
  const float* U0 = (const float*)d_in[1];
  const float* Vg0 = (const float*)d_in[2];
  const float* bg0 = (const float*)d_in[3];
  const float* U1 = (const float*)d_in[4];
  const float* Vg1 = (const float*)d_in[5];
  const float* bg1 = (const float*)d_in[6];
  const float* U2 = (const float*)d_in[7];
  const float* Vg2 = (const float*)d_in[8];
  const float* bg2 = (const float*)d_in[9];
  const float* U3 = (const float*)d_in[10];
  const float* Vg3 = (const float*)d_in[11];
  const float* bg3 = (const float*)d_in[12];

  if (ws_size < WS_NEED) return;  // diagnostic: leaves d_out poisoned

  char* ws = (char*)d_ws;
  short* Wt = (short*)(ws + OFF_WT);
  short* xb = (short*)(ws + OFF_XB);
  short* hb = (short*)(ws + OFF_HB);

  (void)hipFuncSetAttribute((const void*)lstm_rec,
                      hipFuncAttributeMaxDynamicSharedMemorySize, LDS_BYTES);

  // parity 0: zeros -> valid h(0)=0, tag 0. parity 1: 0x0101 -> stale until h(1) lands.
  (void)hipMemsetAsync(ws + OFF_HB, 0x00, 131072, stream);
  (void)hipMemsetAsync(ws + OFF_HB + 131072, 0x01, 131072, stream);
  pack_w_kernel<<<dim3(64, 24), 256, 0, stream>>>(U0, U1, U2, U3, Vg0, Vg1, Vg2, Vg3, Wt);
  xcvt<<<dim3(2048), 256, 0, stream>>>(x, xb);
  lstm_rec<<<dim3(GROUPS * GBLK), 512, LDS_BYTES, stream>>>(
      Wt, xb, bg0, bg1, bg2, bg3, hb, (float*)d_out);
}

// Round 13
// 2315.833 us; speedup vs baseline: 1.3441x; 1.0908x over previous
//
#include <hip/hip_runtime.h>
#include <stdint.h>

#define B_  64
#define T_  512
#define I_  512
#define H_  1024
#define KW  1536   // rows of W_t = I_ + H_

#define GROUPS 4
#define GBLK   64    // col-blocks per group
#define MBR    16    // batch rows per group

#define LDS_BYTES 49408   // 32 KiB sh + 16640 B gl

typedef __attribute__((ext_vector_type(8))) short bf16x8;
typedef __attribute__((ext_vector_type(4))) float f32x4;

// ---- ws layout (bytes) ----
#define OFF_WT   ((size_t)0)                        // 4096*1536*2 = 12,582,912
#define OFF_XB   ((size_t)(16u << 20))              // x bf16 frag-order: 33,554,432
#define OFF_HB   (OFF_XB + (size_t)33554432)        // tagged h: 2 par * 4 grp * 16 * 1024 * 2B
#define WS_NEED  (OFF_HB + (size_t)262144)

__device__ __forceinline__ unsigned short f2bf(float x) {
  unsigned u = __float_as_uint(x);
  u += 0x7FFFu + ((u >> 16) & 1u);        // RNE
  return (unsigned short)(u >> 16);
}
__device__ __forceinline__ float sigm(float x) {
  return 1.0f / (1.0f + __expf(-x));
}
__device__ __forceinline__ float fast_tanh(float x) {
  const float e2 = __expf(2.0f * x);
  return 1.0f - 2.0f / (e2 + 1.0f);
}
__device__ __forceinline__ bf16x8 bc8(int4 v) {
  union { int4 i; bf16x8 b; } u; u.i = v; return u.b;
}

// ============ kernel 0: pack [U;V] -> W_t[col][k] bf16 (transposed) ============
__global__ __launch_bounds__(256) void pack_w_kernel(
    const float* __restrict__ U0, const float* __restrict__ U1,
    const float* __restrict__ U2, const float* __restrict__ U3,
    const float* __restrict__ V0, const float* __restrict__ V1,
    const float* __restrict__ V2, const float* __restrict__ V3,
    short* __restrict__ Wt)
{
  __shared__ short sl[64][65];
  const int c0 = blockIdx.x * 64;
  const int k0 = blockIdx.y * 64;
  const int g  = c0 >> 10;
  const int h0 = c0 & 1023;
  const float* srcU = (g == 0 ? U0 : g == 1 ? U1 : g == 2 ? U2 : U3);
  const float* srcV = (g == 0 ? V0 : g == 1 ? V1 : g == 2 ? V2 : V3);
  const float* src  = (k0 < 512) ? (srcU + (size_t)k0 * H_)
                                 : (srcV + (size_t)(k0 - 512) * H_);
  const int tid = threadIdx.x;
  const int cl = tid & 63;
  const int r4 = tid >> 6;
  #pragma unroll
  for (int r = 0; r < 16; ++r) {
    const int kl = r * 4 + r4;
    sl[kl][cl] = (short)f2bf(src[(size_t)kl * H_ + h0 + cl]);
  }
  __syncthreads();
  #pragma unroll
  for (int r = 0; r < 16; ++r) {
    const int cl2 = r * 4 + r4;
    Wt[(size_t)(c0 + cl2) * KW + k0 + cl] = sl[cl][cl2];
  }
}

// ============ kernel 1: x fp32 -> bf16, PER-WAVE FRAGMENT ORDER ============
// xb[t][g][F*8 + e], F = unit*64 + slot, unit = k>>5, slot = row*4 + (k>>3)&3
// so lstm_rec wave kq, lane (cit,l16) reads frag j at xb + tg*8192 + ((kq*4+j)*64 + cit*4+l16)*8
__global__ __launch_bounds__(256) void xcvt(
    const float* __restrict__ x, short* __restrict__ xb)
{
  const int gid = blockIdx.x;              // 8192 = 512 t * 4 g * 4 quarters
  const int q  = gid & 3;
  const int tg = gid >> 2;                 // t*4 + g
  const int t  = tg >> 2, g = tg & 3;
  const int F  = q * 256 + threadIdx.x;    // frag id 0..1023
  const int unit = F >> 6, slot = F & 63;
  const int row = slot >> 2, l8 = (slot & 3) * 8;
  const float* src = x + ((size_t)(g * 16 + row) * T_ + t) * I_ + unit * 32 + l8;
  const float4 v0 = *(const float4*)(src);
  const float4 v1 = *(const float4*)(src + 4);
  int4 pk;
  pk.x = (int)((unsigned)f2bf(v0.x) | ((unsigned)f2bf(v0.y) << 16));
  pk.y = (int)((unsigned)f2bf(v0.z) | ((unsigned)f2bf(v0.w) << 16));
  pk.z = (int)((unsigned)f2bf(v1.x) | ((unsigned)f2bf(v1.y) << 16));
  pk.w = (int)((unsigned)f2bf(v1.z) | ((unsigned)f2bf(v1.w) << 16));
  *(int4*)(xb + (size_t)tg * 8192 + (size_t)F * 8) = pk;
}

// fragment address (shorts): slot XOR-swizzled within unit
#define FR_ADDR(unit, slot) ((((unit) * 64) + ((slot) ^ ((unit) & 7))) * 8)

#define MFMA_ __builtin_amdgcn_mfma_f32_16x16x32_bf16

// ============ kernel 2: persistent recurrence; V in regs; frag-order x direct ============
__global__ __launch_bounds__(512, 1) void lstm_rec(
    const short* __restrict__ Wt, const short* __restrict__ xb,
    const float* __restrict__ b0g, const float* __restrict__ b1g,
    const float* __restrict__ b2g, const float* __restrict__ b3g,
    short* __restrict__ hb, float* __restrict__ out)
{
  extern __shared__ char smem[];
  short* sh = (short*)smem;                 // 32 KiB h frags (32 units x 64 slots x 16B)
  float* gl = (float*)(smem + 32768);       // [16 rows][260] f32 partial-gate exchange

  const int tid = threadIdx.x;
  const int blk = blockIdx.x;
  const int g   = blk >> 6;                 // group (16 batch rows)
  const int bi  = blk & 63;
  const int base = bi * 16;                 // 16 h-cols per block per gate
  const int b0  = g * MBR;

  const int w = tid >> 6, l = tid & 63;
  const int kq = w & 3;                     // K quarter (256 of V-K, 128 of x-K)
  const int np = w >> 2;                    // col half: gates {2np, 2np+1}
  const int cit = l & 15;
  const int l16 = l >> 4;
  const int slot_r = (cit << 2) | l16;

  // ---- one-time: V fragments -> 64 VGPRs, U fragments -> 32 VGPRs ----
  bf16x8 vfr[2][8];
  bf16x8 ufr[2][4];
  #pragma unroll
  for (int n = 0; n < 2; ++n) {
    const int col = (np * 2 + n) * 1024 + base + cit;
    const short* wp = Wt + (size_t)col * KW;
    #pragma unroll
    for (int j = 0; j < 8; ++j)
      vfr[n][j] = *(const bf16x8*)(wp + 512 + kq * 256 + j * 32 + l16 * 8);
    #pragma unroll
    for (int j = 0; j < 4; ++j)
      ufr[n][j] = *(const bf16x8*)(wp + kq * 128 + j * 32 + l16 * 8);
  }

  const float* bias0 = (np == 0) ? b0g : b2g;
  const float* bias1 = (np == 0) ? b1g : b3g;
  const float bv0 = (kq == 0) ? bias0[base + cit] : 0.0f;
  const float bv1 = (kq == 0) ? bias1[base + cit] : 0.0f;

  const int crow = tid >> 4;                // combine row (tid<256)
  const int ccj  = tid & 15;

  // x fragment base: frag-order layout -> per-wave contiguous, compiler loads
  const short* xg = xb + (size_t)g * 8192 + (size_t)((kq * 4) * 64 + slot_r) * 8;
  // frag j of step t at: xg + (size_t)t * 32768 + j * 512

  float c_state = 0.0f;
  int4 nx0, nx1, nx2, nx3;                  // x(t+1) fragments (compiler-managed)
  f32x4 xacc0, xacc1;

  // ---- prologue: xu(0); prefetch x(1) ----
  {
    const int4 a0 = *(const int4*)(xg + 0 * 512);
    const int4 a1 = *(const int4*)(xg + 1 * 512);
    const int4 a2 = *(const int4*)(xg + 2 * 512);
    const int4 a3 = *(const int4*)(xg + 3 * 512);
    xacc0 = (f32x4){bv0, bv0, bv0, bv0};
    xacc1 = (f32x4){bv1, bv1, bv1, bv1};
    xacc0 = MFMA_(bc8(a0), ufr[0][0], xacc0, 0, 0, 0);
    xacc1 = MFMA_(bc8(a0), ufr[1][0], xacc1, 0, 0, 0);
    xacc0 = MFMA_(bc8(a1), ufr[0][1], xacc0, 0, 0, 0);
    xacc1 = MFMA_(bc8(a1), ufr[1][1], xacc1, 0, 0, 0);
    xacc0 = MFMA_(bc8(a2), ufr[0][2], xacc0, 0, 0, 0);
    xacc1 = MFMA_(bc8(a2), ufr[1][2], xacc1, 0, 0, 0);
    xacc0 = MFMA_(bc8(a3), ufr[0][3], xacc0, 0, 0, 0);
    xacc1 = MFMA_(bc8(a3), ufr[1][3], xacc1, 0, 0, 0);
  }
  nx0 = *(const int4*)(xg + (size_t)1 * 32768 + 0 * 512);
  nx1 = *(const int4*)(xg + (size_t)1 * 32768 + 1 * 512);
  nx2 = *(const int4*)(xg + (size_t)1 * 32768 + 2 * 512);
  nx3 = *(const int4*)(xg + (size_t)1 * 32768 + 3 * 512);

  for (int t = 0; t < T_; ++t) {
    { // ---- A: retry-load h(t) until step-tag bits match, then stage to sh ----
      const unsigned expw = ((t >> 1) & 1) ? 0x00010001u : 0u;
      const short* hsrc = hb + ((size_t)(t & 1) * GROUPS + g) * (MBR * H_);
      int4 v0, v1, v2, v3;
      for (;;) {
        #define LDC(ii, vv) { \
          const short* p = hsrc + (size_t)((((ii) * 512 + tid) >> 7)) * H_ \
                           + ((((ii) * 512 + tid) & 127) * 8); \
          asm volatile("global_load_dwordx4 %0, %1, off sc0 sc1" : "=&v"(vv) : "v"(p)); }
        LDC(0, v0) LDC(1, v1) LDC(2, v2) LDC(3, v3)
        #undef LDC
        asm volatile("s_waitcnt vmcnt(0)" ::: "memory");
        __builtin_amdgcn_sched_barrier(0);
        #define XR(vv) (((unsigned)(vv).x ^ expw) | ((unsigned)(vv).y ^ expw) | \
                        ((unsigned)(vv).z ^ expw) | ((unsigned)(vv).w ^ expw))
        const unsigned diff = (XR(v0) | XR(v1) | XR(v2) | XR(v3)) & 0x00010001u;
        #undef XR
        if (__all(diff == 0u)) break;
        asm volatile("s_sleep 1" ::: "memory");
      }
      #define STC(ii, vv) { const int f = (ii) * 512 + tid; const int row = f >> 7; \
        const int k0s = (f & 127) * 8; \
        *(int4*)(sh + FR_ADDR(k0s >> 5, (row << 2) | ((k0s >> 3) & 3))) = vv; }
      STC(0, v0) STC(1, v1) STC(2, v2) STC(3, v3)
      #undef STC
    }
    __syncthreads();                                   // barrier 1

    // ---- B: partial gates = xu_part + h @ V_part (V from registers) ----
    f32x4 acc0 = xacc0, acc1 = xacc1;
    #pragma unroll
    for (int j = 0; j < 8; ++j) {
      const bf16x8 af = *(const bf16x8*)(sh + FR_ADDR(kq * 8 + j, slot_r));
      acc0 = MFMA_(af, vfr[0][j], acc0, 0, 0, 0);
      acc1 = MFMA_(af, vfr[1][j], acc1, 0, 0, 0);
    }

    // ---- C: 4-way partial exchange ----
    #pragma unroll
    for (int i = 0; i < 4; ++i) {
      gl[(l16 * 4 + i) * 260 + kq * 64 + (np * 2 + 0) * 16 + cit] = acc0[i];
      gl[(l16 * 4 + i) * 260 + kq * 64 + (np * 2 + 1) * 16 + cit] = acc1[i];
    }
    __syncthreads();                                   // barrier 2

    // ---- D: combine; fire-and-forget tagged h stores; out stores ----
    if (tid < 256) {
      const float* gr = gl + crow * 260;
      float s[4];
      #pragma unroll
      for (int gate = 0; gate < 4; ++gate)
        s[gate] = gr[0 * 64 + gate * 16 + ccj] + gr[1 * 64 + gate * 16 + ccj]
                + gr[2 * 64 + gate * 16 + ccj] + gr[3 * 64 + gate * 16 + ccj];
      const float i_ = sigm(s[0]), f_ = sigm(s[1]), g_ = sigm(s[2]), o_ = sigm(s[3]);
      c_state = f_ * c_state + i_ * g_;
      const float hval = o_ * fast_tanh(c_state);
      if (t + 1 < T_) {
        unsigned hv = (unsigned)f2bf(hval);
        hv = (hv & ~1u) | (unsigned)(((t + 1) >> 1) & 1);   // steal LSB as step tag
        short* hdst = hb + ((size_t)((t + 1) & 1) * GROUPS + g) * (MBR * H_)
                      + (size_t)crow * H_ + base + ccj;
        asm volatile("global_store_short %0, %1, off sc0 sc1" :: "v"(hdst), "v"(hv) : "memory");
      }
      out[((size_t)(b0 + crow) << 19) + (size_t)t * H_ + base + ccj] = hval;
      if (t == T_ - 1) {
        out[(size_t)B_ * T_ * H_ + (size_t)(b0 + crow) * H_ + base + ccj] = hval;
        out[(size_t)B_ * T_ * H_ + (size_t)B_ * H_ + (size_t)(b0 + crow) * H_ + base + ccj] = c_state;
      }
    }

    if (t + 1 < T_) {
      // ---- F: xu(t+1) from prefetched x regs (compiler-managed waits);
      //         then prefetch x(t+2) ----
      const int4 c0 = nx0, c1 = nx1, c2 = nx2, c3 = nx3;
      xacc0 = (f32x4){bv0, bv0, bv0, bv0};
      xacc1 = (f32x4){bv1, bv1, bv1, bv1};
      xacc0 = MFMA_(bc8(c0), ufr[0][0], xacc0, 0, 0, 0);
      xacc1 = MFMA_(bc8(c0), ufr[1][0], xacc1, 0, 0, 0);
      xacc0 = MFMA_(bc8(c1), ufr[0][1], xacc0, 0, 0, 0);
      xacc1 = MFMA_(bc8(c1), ufr[1][1], xacc1, 0, 0, 0);
      xacc0 = MFMA_(bc8(c2), ufr[0][2], xacc0, 0, 0, 0);
      xacc1 = MFMA_(bc8(c2), ufr[1][2], xacc1, 0, 0, 0);
      xacc0 = MFMA_(bc8(c3), ufr[0][3], xacc0, 0, 0, 0);
      xacc1 = MFMA_(bc8(c3), ufr[1][3], xacc1, 0, 0, 0);
      {
        const size_t tn = (size_t)((t + 2 < T_) ? t + 2 : T_ - 1);
        const short* xp = xg + tn * 32768;
        nx0 = *(const int4*)(xp + 0 * 512);
        nx1 = *(const int4*)(xp + 1 * 512);
        nx2 = *(const int4*)(xp + 2 * 512);
        nx3 = *(const int4*)(xp + 3 * 512);
      }
    }
  }
}

extern "C" void kernel_launch(void* const* d_in, const int* in_sizes, int n_in,
                              void* d_out, int out_size, void* d_ws, size_t ws_size,
                              hipStream_t stream)
{
  const float* x  = (const float*)d_in[0];
  const float* U0 = (const float*)d_in[1];
  const float* Vg0 = (const float*)d_in[2];
  const float* bg0 = (const float*)d_in[3];
  const float* U1 = (const float*)d_in[4];
  const float* Vg1 = (const float*)d_in[5];
  const float* bg1 = (const float*)d_in[6];
  const float* U2 = (const float*)d_in[7];
  const float* Vg2 = (const float*)d_in[8];
  const float* bg2 = (const float*)d_in[9];
  const float* U3 = (const float*)d_in[10];
  const float* Vg3 = (const float*)d_in[11];
  const float* bg3 = (const float*)d_in[12];

  if (ws_size < WS_NEED) return;  // diagnostic: leaves d_out poisoned

  char* ws = (char*)d_ws;
  short* Wt = (short*)(ws + OFF_WT);
  short* xb = (short*)(ws + OFF_XB);
  short* hb = (short*)(ws + OFF_HB);

  (void)hipFuncSetAttribute((const void*)lstm_rec,
                      hipFuncAttributeMaxDynamicSharedMemorySize, LDS_BYTES);

  // parity 0: zeros -> valid h(0)=0, tag 0. parity 1: 0x0101 -> stale until h(1) lands.
  (void)hipMemsetAsync(ws + OFF_HB, 0x00, 131072, stream);
  (void)hipMemsetAsync(ws + OFF_HB + 131072, 0x01, 131072, stream);
  pack_w_kernel<<<dim3(64, 24), 256, 0, stream>>>(U0, U1, U2, U3, Vg0, Vg1, Vg2, Vg3, Wt);
  xcvt<<<dim3(8192), 256, 0, stream>>>(x, xb);
  lstm_rec<<<dim3(GROUPS * GBLK), 512, LDS_BYTES, stream>>>(
      Wt, xb, bg0, bg1, bg2, bg3, hb, (float*)d_out);
}

// Round 14
// 1121.882 us; speedup vs baseline: 2.7745x; 2.0642x over previous
//
#include <hip/hip_runtime.h>
#include <stdint.h>

#define B_  64
#define T_  512
#define I_  512
#define H_  1024
#define G4  4096
#define KW  1536   // rows of W_t = I_ + H_

#define GROUPS 4
#define GBLK   64    // col-blocks per group
#define MBR    16    // batch rows per group

#define LDS_BYTES 66048

typedef __attribute__((ext_vector_type(8))) short bf16x8;
typedef __attribute__((ext_vector_type(4))) float f32x4;

// ---- ws layout (bytes) ----
#define OFF_WT   ((size_t)0)                        // 4096*1536*2 = 12,582,912
#define OFF_XB   ((size_t)(16u << 20))              // x bf16: 64*512*512*2 = 33,554,432
#define OFF_HB   (OFF_XB + (size_t)33554432)        // tagged h: 2 par * 4 grp * 16 * 1024 * 2B = 262,144
#define WS_NEED  (OFF_HB + (size_t)262144)

__device__ __forceinline__ unsigned short f2bf(float x) {
  unsigned u = __float_as_uint(x);
  u += 0x7FFFu + ((u >> 16) & 1u);        // RNE
  return (unsigned short)(u >> 16);
}
__device__ __forceinline__ float sigm(float x) {
  return 1.0f / (1.0f + __expf(-x));
}
__device__ __forceinline__ float fast_tanh(float x) {
  const float e2 = __expf(2.0f * x);
  return 1.0f - 2.0f / (e2 + 1.0f);
}

// ============ kernel 0: pack [U;V] -> W_t[col][k] bf16 (transposed) ============
__global__ __launch_bounds__(256) void pack_w_kernel(
    const float* __restrict__ U0, const float* __restrict__ U1,
    const float* __restrict__ U2, const float* __restrict__ U3,
    const float* __restrict__ V0, const float* __restrict__ V1,
    const float* __restrict__ V2, const float* __restrict__ V3,
    short* __restrict__ Wt)
{
  __shared__ short sl[64][65];
  const int c0 = blockIdx.x * 64;
  const int k0 = blockIdx.y * 64;
  const int g  = c0 >> 10;
  const int h0 = c0 & 1023;
  const float* srcU = (g == 0 ? U0 : g == 1 ? U1 : g == 2 ? U2 : U3);
  const float* srcV = (g == 0 ? V0 : g == 1 ? V1 : g == 2 ? V2 : V3);
  const float* src  = (k0 < 512) ? (srcU + (size_t)k0 * H_)
                                 : (srcV + (size_t)(k0 - 512) * H_);
  const int tid = threadIdx.x;
  const int cl = tid & 63;
  const int r4 = tid >> 6;
  #pragma unroll
  for (int r = 0; r < 16; ++r) {
    const int kl = r * 4 + r4;
    sl[kl][cl] = (short)f2bf(src[(size_t)kl * H_ + h0 + cl]);
  }
  __syncthreads();
  #pragma unroll
  for (int r = 0; r < 16; ++r) {
    const int cl2 = r * 4 + r4;
    Wt[(size_t)(c0 + cl2) * KW + k0 + cl] = sl[cl][cl2];
  }
}

// ============ kernel 1: x fp32 -> bf16 ============
__global__ __launch_bounds__(256) void xcvt(
    const float* __restrict__ x, short* __restrict__ xb)
{
  const int nt = 524288;
  const int idx = blockIdx.x * 256 + threadIdx.x;
  #pragma unroll
  for (int i = 0; i < 8; ++i) {
    const int j = idx + i * nt;
    const float4 v = ((const float4*)x)[j];
    uint2 pk;
    pk.x = (unsigned)f2bf(v.x) | ((unsigned)f2bf(v.y) << 16);
    pk.y = (unsigned)f2bf(v.z) | ((unsigned)f2bf(v.w) << 16);
    ((uint2*)xb)[j] = pk;
  }
}

// fragment address (shorts): slot XOR-swizzled within unit
#define FR_ADDR(unit, slot) ((((unit) * 64) + ((slot) ^ ((unit) & 7))) * 8)

// ============ kernel 2: persistent recurrence; V in regs; tag-in-data sync ============
__global__ __launch_bounds__(512, 2) void lstm_rec(
    const short* __restrict__ Wt, const short* __restrict__ xb,
    const float* __restrict__ b0g, const float* __restrict__ b1g,
    const float* __restrict__ b2g, const float* __restrict__ b3g,
    short* __restrict__ hb, float* __restrict__ out)
{
  extern __shared__ char smem[];
  short* sh = (short*)smem;                 // 32 KiB h frags (32 units x 64 slots x 16B)
  short* sx = (short*)(smem + 32768);       // 16 KiB x frags (16 units)
  float* gl = (float*)(smem + 49152);       // [16 rows][260] f32 partial-gate exchange

  const int tid = threadIdx.x;
  const int blk = blockIdx.x;
  const int g   = blk >> 6;                 // group (16 batch rows)
  const int bi  = blk & 63;
  const int base = bi * 16;                 // 16 h-cols per block per gate
  const int b0  = g * MBR;

  const int w = tid >> 6, l = tid & 63;
  const int kq = w & 3;                     // K quarter (256 of V-K, 128 of x-K)
  const int np = w >> 2;                    // col half: gates {2np, 2np+1}
  const int cit = l & 15;
  const int l16 = l >> 4;
  const int slot_r = (cit << 2) | l16;

  // ---- one-time: V fragments -> 64 VGPRs, U fragments -> 32 VGPRs ----
  bf16x8 vfr[2][8];
  bf16x8 ufr[2][4];
  #pragma unroll
  for (int n = 0; n < 2; ++n) {
    const int col = (np * 2 + n) * 1024 + base + cit;
    const short* wp = Wt + (size_t)col * KW;
    #pragma unroll
    for (int j = 0; j < 8; ++j)
      vfr[n][j] = *(const bf16x8*)(wp + 512 + kq * 256 + j * 32 + l16 * 8);
    #pragma unroll
    for (int j = 0; j < 4; ++j)
      ufr[n][j] = *(const bf16x8*)(wp + kq * 128 + j * 32 + l16 * 8);
  }

  const float* bias0 = (np == 0) ? b0g : b2g;
  const float* bias1 = (np == 0) ? b1g : b3g;
  const float bv0 = (kq == 0) ? bias0[base + cit] : 0.0f;
  const float bv1 = (kq == 0) ? bias1[base + cit] : 0.0f;

  const int crow = tid >> 4;                // combine row (tid<256)
  const int ccj  = tid & 15;

  // x-staging geometry (two 16B fragments per thread)
  const int xr0_row = tid >> 6;
  const int xr1_row = 8 + (tid >> 6);
  const int x_k0 = (tid & 63) * 8;
  const int x_unit = x_k0 >> 5;
  const int xr0_addr = FR_ADDR(x_unit, (xr0_row << 2) | (tid & 3));
  const int xr1_addr = FR_ADDR(x_unit, (xr1_row << 2) | (tid & 3));
  const short* xsrc0 = xb + (size_t)(b0 + xr0_row) * T_ * I_ + x_k0;
  const short* xsrc1 = xb + (size_t)(b0 + xr1_row) * T_ * I_ + x_k0;

  float c_state = 0.0f;

  // ---- prologue: stage x(0), xu(0), prefetch x(1) ----
  *(int4*)(sx + xr0_addr) = *(const int4*)(xsrc0);
  *(int4*)(sx + xr1_addr) = *(const int4*)(xsrc1);
  __syncthreads();
  f32x4 xacc0 = (f32x4){bv0, bv0, bv0, bv0};
  f32x4 xacc1 = (f32x4){bv1, bv1, bv1, bv1};
  #pragma unroll
  for (int j = 0; j < 4; ++j) {
    const bf16x8 xf = *(const bf16x8*)(sx + FR_ADDR(kq * 4 + j, slot_r));
    xacc0 = __builtin_amdgcn_mfma_f32_16x16x32_bf16(xf, ufr[0][j], xacc0, 0, 0, 0);
    xacc1 = __builtin_amdgcn_mfma_f32_16x16x32_bf16(xf, ufr[1][j], xacc1, 0, 0, 0);
  }
  int4 xr0 = *(const int4*)(xsrc0 + (size_t)1 * I_);
  int4 xr1 = *(const int4*)(xsrc1 + (size_t)1 * I_);

  for (int t = 0; t < T_; ++t) {
    { // ---- A: retry-load h(t) until step-tag bits match, then stage to sh ----
      const unsigned expw = ((t >> 1) & 1) ? 0x00010001u : 0u;
      const short* hsrc = hb + ((size_t)(t & 1) * GROUPS + g) * (MBR * H_);
      int4 v0, v1, v2, v3;
      for (;;) {
        #define LDC(ii, vv) { \
          const short* p = hsrc + (size_t)((((ii) * 512 + tid) >> 7)) * H_ \
                           + ((((ii) * 512 + tid) & 127) * 8); \
          asm volatile("global_load_dwordx4 %0, %1, off sc0 sc1" : "=&v"(vv) : "v"(p)); }
        LDC(0, v0) LDC(1, v1) LDC(2, v2) LDC(3, v3)
        #undef LDC
        asm volatile("s_waitcnt vmcnt(0)" ::: "memory");
        __builtin_amdgcn_sched_barrier(0);
        #define XR(vv) (((unsigned)(vv).x ^ expw) | ((unsigned)(vv).y ^ expw) | \
                        ((unsigned)(vv).z ^ expw) | ((unsigned)(vv).w ^ expw))
        const unsigned diff = (XR(v0) | XR(v1) | XR(v2) | XR(v3)) & 0x00010001u;
        #undef XR
        if (__all(diff == 0u)) break;
        asm volatile("s_sleep 1" ::: "memory");
      }
      #define STC(ii, vv) { const int f = (ii) * 512 + tid; const int row = f >> 7; \
        const int k0s = (f & 127) * 8; \
        *(int4*)(sh + FR_ADDR(k0s >> 5, (row << 2) | ((k0s >> 3) & 3))) = vv; }
      STC(0, v0) STC(1, v1) STC(2, v2) STC(3, v3)
      #undef STC
    }
    __syncthreads();                                   // barrier 1

    // ---- B: partial gates = xu_part + h @ V_part (V from registers) ----
    f32x4 acc0 = xacc0, acc1 = xacc1;
    #pragma unroll
    for (int j = 0; j < 8; ++j) {
      const bf16x8 af = *(const bf16x8*)(sh + FR_ADDR(kq * 8 + j, slot_r));
      acc0 = __builtin_amdgcn_mfma_f32_16x16x32_bf16(af, vfr[0][j], acc0, 0, 0, 0);
      acc1 = __builtin_amdgcn_mfma_f32_16x16x32_bf16(af, vfr[1][j], acc1, 0, 0, 0);
    }

    // ---- C: 4-way partial exchange ----
    #pragma unroll
    for (int i = 0; i < 4; ++i) {
      gl[(l16 * 4 + i) * 260 + kq * 64 + (np * 2 + 0) * 16 + cit] = acc0[i];
      gl[(l16 * 4 + i) * 260 + kq * 64 + (np * 2 + 1) * 16 + cit] = acc1[i];
    }
    __syncthreads();                                   // barrier 2

    // ---- D: combine; fire-and-forget tagged h stores; out stores ----
    if (tid < 256) {
      const float* gr = gl + crow * 260;
      float s[4];
      #pragma unroll
      for (int gate = 0; gate < 4; ++gate)
        s[gate] = gr[0 * 64 + gate * 16 + ccj] + gr[1 * 64 + gate * 16 + ccj]
                + gr[2 * 64 + gate * 16 + ccj] + gr[3 * 64 + gate * 16 + ccj];
      const float i_ = sigm(s[0]), f_ = sigm(s[1]), g_ = sigm(s[2]), o_ = sigm(s[3]);
      c_state = f_ * c_state + i_ * g_;
      const float hval = o_ * fast_tanh(c_state);
      if (t + 1 < T_) {
        unsigned hv = (unsigned)f2bf(hval);
        hv = (hv & ~1u) | (unsigned)(((t + 1) >> 1) & 1);   // steal LSB as step tag
        short* hdst = hb + ((size_t)((t + 1) & 1) * GROUPS + g) * (MBR * H_)
                      + (size_t)crow * H_ + base + ccj;
        asm volatile("global_store_short %0, %1, off sc0 sc1" :: "v"(hdst), "v"(hv) : "memory");
      }
      out[((size_t)(b0 + crow) << 19) + (size_t)t * H_ + base + ccj] = hval;
      if (t == T_ - 1) {
        out[(size_t)B_ * T_ * H_ + (size_t)(b0 + crow) * H_ + base + ccj] = hval;
        out[(size_t)B_ * T_ * H_ + (size_t)B_ * H_ + (size_t)(b0 + crow) * H_ + base + ccj] = c_state;
      }
    }

    if (t + 1 < T_) {
      // ---- E: write prefetched x(t+1), prefetch x(t+2) ----
      *(int4*)(sx + xr0_addr) = xr0;
      *(int4*)(sx + xr1_addr) = xr1;
      {
        const size_t tn = (size_t)((t + 2 < T_) ? t + 2 : T_ - 1);
        xr0 = *(const int4*)(xsrc0 + tn * I_);
        xr1 = *(const int4*)(xsrc1 + tn * I_);
      }
      __syncthreads();                                 // barrier 3

      // ---- F: xu(t+1) partial = bias + x(t+1) @ U_part ----
      xacc0 = (f32x4){bv0, bv0, bv0, bv0};
      xacc1 = (f32x4){bv1, bv1, bv1, bv1};
      #pragma unroll
      for (int j = 0; j < 4; ++j) {
        const bf16x8 xf = *(const bf16x8*)(sx + FR_ADDR(kq * 4 + j, slot_r));
        xacc0 = __builtin_amdgcn_mfma_f32_16x16x32_bf16(xf, ufr[0][j], xacc0, 0, 0, 0);
        xacc1 = __builtin_amdgcn_mfma_f32_16x16x32_bf16(xf, ufr[1][j], xacc1, 0, 0, 0);
      }
    }
  }
}

extern "C" void kernel_launch(void* const* d_in, const int* in_sizes, int n_in,
                              void* d_out, int out_size, void* d_ws, size_t ws_size,
                              hipStream_t stream)
{
  const float* x  = (const float*)d_in[0];
  const float* U0 = (const float*)d_in[1];
  const float* Vg0 = (const float*)d_in[2];
  const float* bg0 = (const float*)d_in[3];
  const float* U1 = (const float*)d_in[4];
  const float* Vg1 = (const float*)d_in[5];
  const float* bg1 = (const float*)d_in[6];
  const float* U2 = (const float*)d_in[7];
  const float* Vg2 = (const float*)d_in[8];
  const float* bg2 = (const float*)d_in[9];
  const float* U3 = (const float*)d_in[10];
  const float* Vg3 = (const float*)d_in[11];
  const float* bg3 = (const float*)d_in[12];

  if (ws_size < WS_NEED) return;  // diagnostic: leaves d_out poisoned

  char* ws = (char*)d_ws;
  short* Wt = (short*)(ws + OFF_WT);
  short* xb = (short*)(ws + OFF_XB);
  short* hb = (short*)(ws + OFF_HB);

  (void)hipFuncSetAttribute((const void*)lstm_rec,
                      hipFuncAttributeMaxDynamicSharedMemorySize, LDS_BYTES);

  // par 0: zeros -> valid h(0)=0 with tag bit 0. par 1: 0x0101 -> stale (bit 1) until h(1) lands.
  (void)hipMemsetAsync(ws + OFF_HB, 0x00, 131072, stream);
  (void)hipMemsetAsync(ws + OFF_HB + 131072, 0x01, 131072, stream);
  pack_w_kernel<<<dim3(64, 24), 256, 0, stream>>>(U0, U1, U2, U3, Vg0, Vg1, Vg2, Vg3, Wt);
  xcvt<<<dim3(2048), 256, 0, stream>>>(x, xb);
  lstm_rec<<<dim3(GROUPS * GBLK), 512, LDS_BYTES, stream>>>(
      Wt, xb, bg0, bg1, bg2, bg3, hb, (float*)d_out);
}